// Round 12
// baseline (427.412 us; speedup 1.0000x reference)
//
#include <hip/hip_runtime.h>

#define D      12
#define ASTR   13     // LDS acc stride (coprime with 32 banks)
#define LOGNPB 7
#define NPB    128    // nodes per bucket
#define CAPBF  5120   // max sub-range (bucket/SPLIT) in LDS, tier-1 (split) path
#define CAPF   9216   // max bucket size in LDS, tier-2 (r7) path
#define EPB    16384  // edges per block for passes A/B
#define ABLK   256
#define SBLK   256
#define CBLK   256
#define SPLIT  2      // blocks per bucket in tier-1 pass C

// involution swizzle for sorted2 (breaks stride bank pattern; applied write+read)
#define SWZ(p) ((p) ^ (((p) >> 5) & 31))

// ---------------- bf16 helpers (validated r6: absmax 0.5 with bf16 messages) ----
static __device__ __forceinline__ unsigned f2bf(float f) {
    union { float f; unsigned u; } v; v.f = f;
    unsigned r = v.u + 0x7FFFu + ((v.u >> 16) & 1u);   // RNE
    return r >> 16;
}
static __device__ __forceinline__ float bf_lo(unsigned u) {
    union { unsigned u; float f; } v; v.u = u << 16; return v.f;
}
static __device__ __forceinline__ float bf_hi(unsigned u) {
    union { unsigned u; float f; } v; v.u = u & 0xFFFF0000u; return v.f;
}

// ---------------- cvt: stream edges f32 -> bf16 (154MB, fits L3) ----------------
__global__ __launch_bounds__(256) void cvt_bf16(
    const float* __restrict__ in, unsigned* __restrict__ outw,
    long n8 /* groups of 8 floats */, long ntot /* total floats */)
{
    long i = (long)blockIdx.x * 256 + threadIdx.x;
    const long stride = (long)gridDim.x * 256;
    for (; i < n8; i += stride) {
        const float4* p = reinterpret_cast<const float4*>(in + i * 8);
        float4 a = p[0], b = p[1];
        uint4 w;
        w.x = f2bf(a.x) | (f2bf(a.y) << 16);
        w.y = f2bf(a.z) | (f2bf(a.w) << 16);
        w.z = f2bf(b.x) | (f2bf(b.y) << 16);
        w.w = f2bf(b.z) | (f2bf(b.w) << 16);
        reinterpret_cast<uint4*>(outw)[i] = w;
    }
    if (blockIdx.x == 0 && threadIdx.x == 0) {
        for (long j = n8 * 8; j < ntot; ++j)
            reinterpret_cast<unsigned short*>(outw)[j] = (unsigned short)f2bf(in[j]);
    }
}

// ---------------- pass A: per-block bucket histogram ----------------
__global__ __launch_bounds__(ABLK) void passA_hist(
    const int* __restrict__ receivers, long E, int nbuck,
    int* __restrict__ cnt /* [nblk][nbuck], row-major */)
{
    extern __shared__ int hist[]; // nbuck ints
    for (int i = threadIdx.x; i < nbuck; i += ABLK) hist[i] = 0;
    __syncthreads();
    long e0 = (long)blockIdx.x * EPB;
    long e1 = e0 + EPB; if (e1 > E) e1 = E;
    for (long e = e0 + threadIdx.x; e < e1; e += ABLK) {
        int r = receivers[e];
        atomicAdd(&hist[r >> LOGNPB], 1);
    }
    __syncthreads();
    int* row = cnt + (long)blockIdx.x * nbuck;
    for (int i = threadIdx.x; i < nbuck; i += ABLK) row[i] = hist[i];
}

// ---------------- pass S1: exclusive scan down each bucket column ----------------
__global__ __launch_bounds__(SBLK) void passS1_colscan(
    int* __restrict__ cnt, int nblk, int nbuck, int* __restrict__ totals)
{
    int b = blockIdx.x;
    int t = threadIdx.x;
    __shared__ int csum[SBLK];
    int per = (nblk + SBLK - 1) / SBLK;
    int i0 = t * per;
    int i1 = i0 + per; if (i1 > nblk) i1 = nblk;
    int s = 0;
    for (int i = i0; i < i1; ++i) s += cnt[(long)i * nbuck + b];
    csum[t] = s;
    __syncthreads();
    for (int off = 1; off < SBLK; off <<= 1) {
        int add = (t >= off) ? csum[t - off] : 0;
        __syncthreads();
        csum[t] += add;
        __syncthreads();
    }
    int run = csum[t] - s;
    for (int i = i0; i < i1; ++i) {
        long a = (long)i * nbuck + b;
        int tmp = cnt[a];
        cnt[a] = run;
        run += tmp;
    }
    if (t == SBLK - 1) totals[b] = csum[SBLK - 1];
}

// ---------------- pass S2: exclusive scan over bucket totals ----------------
__global__ __launch_bounds__(1024) void passS2_basescan(
    const int* __restrict__ totals, int* __restrict__ base, int nbuck)
{
    __shared__ int sh[1024];
    int t = threadIdx.x;
    int v = (t < nbuck) ? totals[t] : 0;
    sh[t] = v;
    __syncthreads();
    for (int off = 1; off < 1024; off <<= 1) {
        int add = (t >= off) ? sh[t - off] : 0;
        __syncthreads();
        sh[t] += add;
        __syncthreads();
    }
    if (t < nbuck) base[t] = sh[t] - v;
}

// ---------------- pass B: scatter edge ids into bucket-sorted order ----------------
__global__ __launch_bounds__(ABLK) void passB_scatter(
    const int* __restrict__ receivers, long E, int nbuck,
    const int* __restrict__ cnt, const int* __restrict__ base,
    unsigned int* __restrict__ sorted)
{
    extern __shared__ int cur[];
    const int* row = cnt + (long)blockIdx.x * nbuck;
    for (int i = threadIdx.x; i < nbuck; i += ABLK) cur[i] = row[i] + base[i];
    __syncthreads();
    long e0 = (long)blockIdx.x * EPB;
    long e1 = e0 + EPB; if (e1 > E) e1 = E;
    for (long e = e0 + threadIdx.x; e < e1; e += ABLK) {
        int r = receivers[e];
        int b = r >> LOGNPB;
        int pos = atomicAdd(&cur[b], 1);
        sorted[pos] = ((unsigned)e << LOGNPB) | (unsigned)(r & (NPB - 1));
    }
}

// -------- helpers --------
__device__ __forceinline__ void build_weights(
    int t,
    const float* __restrict__ bn_scale, const float* __restrict__ bn_bias,
    const float* __restrict__ bn_mean,  const float* __restrict__ bn_var,
    const float* __restrict__ W1, const float* __restrict__ b1,
    const float* __restrict__ W2, const float* __restrict__ b2,
    float* sW1, float* sW2, float* sB1, float* sB2)
{
    if (t < D * D) {
        int d = t / D;
        float a = bn_scale[d] * rsqrtf(bn_var[d] + 1e-5f);
        sW1[t] = a * W1[t];
        sW2[t] = W2[t];
    }
    if (t < D) {
        float acc = b1[t];
        #pragma unroll
        for (int d = 0; d < D; ++d) {
            float a = bn_scale[d] * rsqrtf(bn_var[d] + 1e-5f);
            float c = bn_bias[d] - bn_mean[d] * a;
            acc += c * W1[d * D + t];
        }
        sB1[t] = acc;
        sB2[t] = b2[t];
    }
}

__device__ __forceinline__ void mlp12(
    const float x[D],
    const float* sW1, const float* sW2, const float* sB1, const float* sB2,
    float y[D])
{
    float h[D];
    #pragma unroll
    for (int j = 0; j < D; ++j) h[j] = sB1[j];
    #pragma unroll
    for (int d = 0; d < D; ++d) {
        float xd = x[d];
        #pragma unroll
        for (int j = 0; j < D; ++j) h[j] = fmaf(xd, sW1[d * D + j], h[j]);
    }
    #pragma unroll
    for (int j = 0; j < D; ++j) h[j] = fmaxf(h[j], 0.f);
    #pragma unroll
    for (int j = 0; j < D; ++j) y[j] = sB2[j];
    #pragma unroll
    for (int d = 0; d < D; ++d) {
        float hd = h[d];
        #pragma unroll
        for (int j = 0; j < D; ++j) y[j] = fmaf(hd, sW2[d * D + j], y[j]);
    }
}

// ---------------- tier-1 pass C: node sort + bf16 L3-resident gather ----------------
// r12: identical structure to r7 (best known good) but gathers 24B bf16 rows
// from the L3-resident converted array (154MB < 256MB Infinity Cache).
// Merged 2nd GEMM + per-node hist*b2 bias (r10-validated). SPLIT=2 for tail.
__global__ __launch_bounds__(CBLK) void passC_bf(
    const uint2* __restrict__ bfrows,   // 3 uint2 per edge row
    const unsigned int* __restrict__ sortedG,
    const int* __restrict__ base, const int* __restrict__ totals,
    const float* __restrict__ bn_scale, const float* __restrict__ bn_bias,
    const float* __restrict__ bn_mean,  const float* __restrict__ bn_var,
    const float* __restrict__ W1, const float* __restrict__ b1,
    const float* __restrict__ W2, const float* __restrict__ b2,
    float* __restrict__ part,   // null => write out directly
    float* __restrict__ out,
    long total /* N*D */, long slab /* floats per split slab */)
{
    __shared__ float sW1[D * D], sW2[D * D], sB1[D], sB2[D];
    __shared__ int hist[NPB];
    __shared__ int off[NPB + 1];
    __shared__ int cur[NPB];
    __shared__ unsigned sorted2[CAPBF];
    __shared__ float facc[NPB * ASTR];

    const int t = threadIdx.x;
    build_weights(t, bn_scale, bn_bias, bn_mean, bn_var, W1, b1, W2, b2,
                  sW1, sW2, sB1, sB2);
    for (int i = t; i < NPB * ASTR; i += CBLK) facc[i] = 0.f;
    if (t < NPB) hist[t] = 0;
    __syncthreads();

    const int b = blockIdx.x;
    const int s = blockIdx.y;
    const int S = gridDim.y;
    const int s0 = base[b];
    const int n  = totals[b];
    const int chunk = (n + S - 1) / S;
    const int g0 = s * chunk;
    int g1 = g0 + chunk; if (g1 > n) g1 = n;
    const int ns = g1 - g0;
    const unsigned* __restrict__ src = sortedG + s0 + g0;

    if (ns > 0 && ns <= CAPBF) {
        // phase 1: node histogram over this sub-range
        for (int k = t; k < ns; k += CBLK)
            atomicAdd(&hist[src[k] & (NPB - 1)], 1);
        __syncthreads();

        // phase 2: exclusive scan over NPB counters
        int myh = (t < NPB) ? hist[t] : 0;
        if (t < NPB) off[t] = myh;
        __syncthreads();
        for (int d2 = 1; d2 < NPB; d2 <<= 1) {
            int add = 0;
            if (t < NPB && t >= d2) add = off[t - d2];
            __syncthreads();
            if (t < NPB) off[t] += add;
            __syncthreads();
        }
        if (t < NPB) cur[t] = off[t] - myh;
        __syncthreads();
        if (t < NPB) off[t] = cur[t];
        if (t == 0) off[NPB] = ns;
        __syncthreads();

        // phase 3: scatter edge indices into node-sorted (swizzled) LDS order
        for (int k = t; k < ns; k += CBLK) {
            unsigned e = src[k];
            int pos = atomicAdd(&cur[e & (NPB - 1)], 1);
            sorted2[SWZ(pos)] = e >> LOGNPB;
        }
        __syncthreads();

        // phase 4: 1-deep prefetched bf16 gather + MLP + register accumulation
        const int per = (ns + CBLK - 1) / CBLK;
        int k0 = t * per;
        int k1 = k0 + per; if (k1 > ns) k1 = ns;
        if (k0 < k1) {
            int cu = 0;
            while (off[cu + 1] <= k0) ++cu;
            int nodeEnd = off[cu + 1];

            float ac[D];
            #pragma unroll
            for (int j = 0; j < D; ++j) ac[j] = 0.f;

            const int kmax = k1 - 1;
            unsigned idx = sorted2[SWZ(k0)];
            const uint2* rp = bfrows + (size_t)idx * 3;
            uint2 r0 = rp[0], r1 = rp[1], r2 = rp[2];

            for (int k = k0; k < k1; ++k) {
                int kn = (k + 1 <= kmax) ? k + 1 : kmax;
                unsigned nidx = sorted2[SWZ(kn)];
                const uint2* q = bfrows + (size_t)nidx * 3;
                uint2 n0 = q[0], n1 = q[1], n2 = q[2];

                if (k >= nodeEnd) {
                    #pragma unroll
                    for (int j = 0; j < D; ++j) {
                        atomicAdd(&facc[cu * ASTR + j], ac[j]);
                        ac[j] = 0.f;
                    }
                    do { ++cu; } while (off[cu + 1] <= k);
                    nodeEnd = off[cu + 1];
                }

                float x[D] = {bf_lo(r0.x), bf_hi(r0.x), bf_lo(r0.y), bf_hi(r0.y),
                              bf_lo(r1.x), bf_hi(r1.x), bf_lo(r1.y), bf_hi(r1.y),
                              bf_lo(r2.x), bf_hi(r2.x), bf_lo(r2.y), bf_hi(r2.y)};
                float h[D];
                #pragma unroll
                for (int j = 0; j < D; ++j) h[j] = sB1[j];
                #pragma unroll
                for (int d = 0; d < D; ++d) {
                    float xd = x[d];
                    #pragma unroll
                    for (int j = 0; j < D; ++j) h[j] = fmaf(xd, sW1[d * D + j], h[j]);
                }
                #pragma unroll
                for (int j = 0; j < D; ++j) h[j] = fmaxf(h[j], 0.f);
                #pragma unroll
                for (int d = 0; d < D; ++d) {
                    float hd = h[d];
                    #pragma unroll
                    for (int j = 0; j < D; ++j) ac[j] = fmaf(hd, sW2[d * D + j], ac[j]);
                }
                r0 = n0; r1 = n1; r2 = n2;
            }
            #pragma unroll
            for (int j = 0; j < D; ++j) atomicAdd(&facc[cu * ASTR + j], ac[j]);
        }
    } else if (ns > 0) {
        // oversized sub-range: per-edge atomic path (bias per-edge; hist stays 0)
        for (int k = t; k < ns; k += CBLK) {
            unsigned e = src[k];
            const uint2* rp = bfrows + (size_t)(e >> LOGNPB) * 3;
            uint2 r0 = rp[0], r1 = rp[1], r2 = rp[2];
            float x[D] = {bf_lo(r0.x), bf_hi(r0.x), bf_lo(r0.y), bf_hi(r0.y),
                          bf_lo(r1.x), bf_hi(r1.x), bf_lo(r1.y), bf_hi(r1.y),
                          bf_lo(r2.x), bf_hi(r2.x), bf_lo(r2.y), bf_hi(r2.y)};
            float y[D];
            mlp12(x, sW1, sW2, sB1, sB2, y);
            int rloc = (int)(e & (NPB - 1));
            #pragma unroll
            for (int j = 0; j < D; ++j) atomicAdd(&facc[rloc * ASTR + j], y[j]);
        }
    }
    __syncthreads();

    if (part != nullptr) {
        float* dst = part + (long)s * slab + (long)b * (NPB * D);
        for (int i = t; i < NPB * D; i += CBLK) {
            int node = i / D, j = i % D;
            dst[i] = facc[node * ASTR + j] + (float)hist[node] * sB2[j];
        }
    } else {
        long obase = (long)b * (NPB * D);
        long cnt_w = total - obase; if (cnt_w > NPB * D) cnt_w = NPB * D;
        for (long i = t; i < cnt_w; i += CBLK) {
            int node = (int)i / D, j = (int)i % D;
            out[obase + i] = facc[node * ASTR + j] + (float)hist[node] * sB2[j];
        }
    }
}

// ---------------- reduce: sum SPLIT partial slabs (float4) ----------------
__global__ __launch_bounds__(CBLK) void reduce_partials(
    const float* __restrict__ part, float* __restrict__ out,
    long total4, long slab4, int S)
{
    long i = (long)blockIdx.x * CBLK + threadIdx.x;
    if (i >= total4) return;
    const float4* p = reinterpret_cast<const float4*>(part);
    float4 v = p[i];
    for (int s = 1; s < S; ++s) {
        float4 w = p[(long)s * slab4 + i];
        v.x += w.x; v.y += w.y; v.z += w.z; v.w += w.w;
    }
    reinterpret_cast<float4*>(out)[i] = v;
}

// ---------------- tier-2 pass C: r7 exact (f32 gather, no split) ----------------
__global__ __launch_bounds__(CBLK) void passC_f32(
    const float* __restrict__ edges,
    const unsigned int* __restrict__ sortedG,
    const int* __restrict__ base, const int* __restrict__ totals,
    const float* __restrict__ bn_scale, const float* __restrict__ bn_bias,
    const float* __restrict__ bn_mean,  const float* __restrict__ bn_var,
    const float* __restrict__ W1, const float* __restrict__ b1,
    const float* __restrict__ W2, const float* __restrict__ b2,
    float* __restrict__ out, long total)
{
    __shared__ float sW1[D * D], sW2[D * D], sB1[D], sB2[D];
    __shared__ int hist[NPB];
    __shared__ int off[NPB + 1];
    __shared__ int cur[NPB];
    __shared__ unsigned sorted2[CAPF];
    __shared__ float facc[NPB * ASTR];

    const int t = threadIdx.x;
    build_weights(t, bn_scale, bn_bias, bn_mean, bn_var, W1, b1, W2, b2,
                  sW1, sW2, sB1, sB2);
    for (int i = t; i < NPB * ASTR; i += CBLK) facc[i] = 0.f;
    if (t < NPB) hist[t] = 0;
    __syncthreads();

    const int b = blockIdx.x;
    const int s0 = base[b];
    const int n  = totals[b];

    if (n <= CAPF) {
        for (int k = t; k < n; k += CBLK)
            atomicAdd(&hist[sortedG[s0 + k] & (NPB - 1)], 1);
        __syncthreads();
        int myh = (t < NPB) ? hist[t] : 0;
        if (t < NPB) off[t] = myh;
        __syncthreads();
        for (int d2 = 1; d2 < NPB; d2 <<= 1) {
            int add = 0;
            if (t < NPB && t >= d2) add = off[t - d2];
            __syncthreads();
            if (t < NPB) off[t] += add;
            __syncthreads();
        }
        if (t < NPB) cur[t] = off[t] - myh;
        __syncthreads();
        if (t < NPB) off[t] = cur[t];
        if (t == 0) off[NPB] = n;
        __syncthreads();
        for (int k = t; k < n; k += CBLK) {
            unsigned e = sortedG[s0 + k];
            int pos = atomicAdd(&cur[e & (NPB - 1)], 1);
            sorted2[SWZ(pos)] = e >> LOGNPB;
        }
        __syncthreads();

        const int per = (n + CBLK - 1) / CBLK;
        int k0 = t * per;
        int k1 = k0 + per; if (k1 > n) k1 = n;
        if (k0 < k1) {
            int cu = 0;
            while (off[cu + 1] <= k0) ++cu;
            int nodeEnd = off[cu + 1];
            float ac[D];
            #pragma unroll
            for (int j = 0; j < D; ++j) ac[j] = 0.f;
            unsigned idx = sorted2[SWZ(k0)];
            const float4* p = reinterpret_cast<const float4*>(edges + (long)idx * D);
            float4 c0 = p[0], c1 = p[1], c2 = p[2];
            for (int k = k0; k < k1; ++k) {
                float4 n0 = c0, n1 = c1, n2 = c2;
                if (k + 1 < k1) {
                    unsigned ix = sorted2[SWZ(k + 1)];
                    const float4* q = reinterpret_cast<const float4*>(edges + (long)ix * D);
                    n0 = q[0]; n1 = q[1]; n2 = q[2];
                }
                if (k >= nodeEnd) {
                    #pragma unroll
                    for (int j = 0; j < D; ++j) {
                        atomicAdd(&facc[cu * ASTR + j], ac[j]);
                        ac[j] = 0.f;
                    }
                    do { ++cu; } while (off[cu + 1] <= k);
                    nodeEnd = off[cu + 1];
                }
                float x[D] = {c0.x, c0.y, c0.z, c0.w, c1.x, c1.y, c1.z, c1.w,
                              c2.x, c2.y, c2.z, c2.w};
                float y[D];
                mlp12(x, sW1, sW2, sB1, sB2, y);
                #pragma unroll
                for (int j = 0; j < D; ++j) ac[j] += y[j];
                c0 = n0; c1 = n1; c2 = n2;
            }
            #pragma unroll
            for (int j = 0; j < D; ++j) atomicAdd(&facc[cu * ASTR + j], ac[j]);
        }
    } else {
        for (int k = t; k < n; k += CBLK) {
            unsigned e = sortedG[s0 + k];
            const float4* p = reinterpret_cast<const float4*>(edges + (long)(e >> LOGNPB) * D);
            float4 c0 = p[0], c1 = p[1], c2 = p[2];
            float x[D] = {c0.x, c0.y, c0.z, c0.w, c1.x, c1.y, c1.z, c1.w,
                          c2.x, c2.y, c2.z, c2.w};
            float y[D];
            mlp12(x, sW1, sW2, sB1, sB2, y);
            int rloc = (int)(e & (NPB - 1));
            #pragma unroll
            for (int j = 0; j < D; ++j) atomicAdd(&facc[rloc * ASTR + j], y[j]);
        }
    }
    __syncthreads();

    long obase = (long)b * (NPB * D);
    long cnt_w = total - obase; if (cnt_w > NPB * D) cnt_w = NPB * D;
    for (long i = t; i < cnt_w; i += CBLK)
        out[obase + i] = facc[((int)i / D) * ASTR + ((int)i % D)];
}

// ---------------- tier-3 fallback: direct atomic scatter ----------------
#define EPT 4
__global__ __launch_bounds__(ABLK) void edge_mlp_scatter(
    const float* __restrict__ edges,
    const float* __restrict__ bn_scale, const float* __restrict__ bn_bias,
    const float* __restrict__ bn_mean,  const float* __restrict__ bn_var,
    const float* __restrict__ W1, const float* __restrict__ b1,
    const float* __restrict__ W2, const float* __restrict__ b2,
    const int* __restrict__ receivers, float* __restrict__ out, long E)
{
    __shared__ float sW1[D * D], sW2[D * D], sB1[D], sB2[D];
    const int t = threadIdx.x;
    build_weights(t, bn_scale, bn_bias, bn_mean, bn_var, W1, b1, W2, b2,
                  sW1, sW2, sB1, sB2);
    __syncthreads();
    const long basee = (long)blockIdx.x * (ABLK * EPT) + t;
    #pragma unroll
    for (int kk = 0; kk < EPT; ++kk) {
        long e = basee + (long)kk * ABLK;
        if (e >= E) continue;
        int r = receivers[e];
        const float4* p = reinterpret_cast<const float4*>(edges + e * D);
        float4 v0 = p[0], v1 = p[1], v2 = p[2];
        float x[D] = {v0.x, v0.y, v0.z, v0.w, v1.x, v1.y, v1.z, v1.w,
                      v2.x, v2.y, v2.z, v2.w};
        float y[D];
        mlp12(x, sW1, sW2, sB1, sB2, y);
        #pragma unroll
        for (int j = 0; j < D; ++j) atomicAdd(&out[(long)r * D + j], y[j]);
    }
}

extern "C" void kernel_launch(void* const* d_in, const int* in_sizes, int n_in,
                              void* d_out, int out_size, void* d_ws, size_t ws_size,
                              hipStream_t stream) {
    const float* edges     = (const float*)d_in[0];
    const float* bn_scale  = (const float*)d_in[1];
    const float* bn_bias   = (const float*)d_in[2];
    const float* bn_mean   = (const float*)d_in[3];
    const float* bn_var    = (const float*)d_in[4];
    const float* W1        = (const float*)d_in[5];
    const float* b1        = (const float*)d_in[6];
    const float* W2        = (const float*)d_in[7];
    const float* b2        = (const float*)d_in[8];
    const int*   receivers = (const int*)d_in[9];
    float*       out       = (float*)d_out;

    const long E = (long)in_sizes[0] / D;
    const int  N = out_size / D;

    const int  nbuck = (N + NPB - 1) >> LOGNPB;
    const long nblk  = (E + EPB - 1) / EPB;
    const size_t cntBytes  = (size_t)nblk * (size_t)nbuck * 4u;
    const size_t head      = cntBytes + 2u * (size_t)nbuck * 4u + 512u;
    const size_t bfBytes   = (size_t)E * 24u;
    const size_t slabBytes = (size_t)nbuck * (size_t)(NPB * D) * 4u;
    const size_t needT1 = head + (size_t)E * 4u + bfBytes + (size_t)SPLIT * slabBytes + 1024u;
    const size_t needT2 = head + (size_t)E * 4u;
    const long total = (long)N * D;

    const bool shapeOK = (nbuck <= 1024) && (E < (1L << 25));
    const size_t lds = (size_t)nbuck * 4u;

    if (shapeOK && ws_size >= needT1) {
        // tier 1: bf16 L3-resident gather
        char* w = (char*)d_ws;
        int* cnt    = (int*)w;  w += cntBytes;
        int* totals = (int*)w;  w += (size_t)nbuck * 4u;
        int* basep  = (int*)w;  w += (size_t)nbuck * 4u;
        unsigned int* sortedG = (unsigned int*)w;  w += (size_t)E * 4u;
        unsigned* bfw = (unsigned*)(((uintptr_t)w + 255u) & ~(uintptr_t)255u);
        w = (char*)bfw + bfBytes;
        float* part = (float*)(((uintptr_t)w + 255u) & ~(uintptr_t)255u);

        const long ntot = E * D;
        const long n8 = ntot / 8;
        cvt_bf16      <<<dim3(2048), dim3(256), 0, stream>>>(edges, bfw, n8, ntot);
        passA_hist    <<<dim3((unsigned)nblk), dim3(ABLK), lds, stream>>>(receivers, E, nbuck, cnt);
        passS1_colscan<<<dim3((unsigned)nbuck), dim3(SBLK), 0, stream>>>(cnt, (int)nblk, nbuck, totals);
        passS2_basescan<<<dim3(1), dim3(1024), 0, stream>>>(totals, basep, nbuck);
        passB_scatter <<<dim3((unsigned)nblk), dim3(ABLK), lds, stream>>>(receivers, E, nbuck, cnt, basep, sortedG);

        const long slab = (long)nbuck * (NPB * D);
        passC_bf      <<<dim3((unsigned)nbuck, SPLIT), dim3(CBLK), 0, stream>>>(
            (const uint2*)bfw, sortedG, basep, totals,
            bn_scale, bn_bias, bn_mean, bn_var, W1, b1, W2, b2,
            part, out, total, slab);
        const long total4 = total / 4;
        const long rblocks = (total4 + CBLK - 1) / CBLK;
        reduce_partials<<<dim3((unsigned)rblocks), dim3(CBLK), 0, stream>>>(
            part, out, total4, slab / 4, SPLIT);
        return;
    }

    if (shapeOK && ws_size >= needT2) {
        // tier 2: r7 exact path
        char* w = (char*)d_ws;
        int* cnt    = (int*)w;  w += cntBytes;
        int* totals = (int*)w;  w += (size_t)nbuck * 4u;
        int* basep  = (int*)w;  w += (size_t)nbuck * 4u;
        unsigned int* sortedG = (unsigned int*)w;

        passA_hist    <<<dim3((unsigned)nblk), dim3(ABLK), lds, stream>>>(receivers, E, nbuck, cnt);
        passS1_colscan<<<dim3((unsigned)nbuck), dim3(SBLK), 0, stream>>>(cnt, (int)nblk, nbuck, totals);
        passS2_basescan<<<dim3(1), dim3(1024), 0, stream>>>(totals, basep, nbuck);
        passB_scatter <<<dim3((unsigned)nblk), dim3(ABLK), lds, stream>>>(receivers, E, nbuck, cnt, basep, sortedG);
        passC_f32     <<<dim3((unsigned)nbuck), dim3(CBLK), 0, stream>>>(
            edges, sortedG, basep, totals,
            bn_scale, bn_bias, bn_mean, bn_var, W1, b1, W2, b2, out, total);
        return;
    }

    (void)hipMemsetAsync(d_out, 0, (size_t)out_size * sizeof(float), stream);
    const long blocks = (E + (long)(ABLK * EPT) - 1) / (long)(ABLK * EPT);
    edge_mlp_scatter<<<dim3((unsigned)blocks), dim3(ABLK), 0, stream>>>(
        edges, bn_scale, bn_bias, bn_mean, bn_var, W1, b1, W2, b2,
        receivers, out, E);
}